// Round 8
// baseline (361.557 us; speedup 1.0000x reference)
//
#include <hip/hip_runtime.h>

#define N_USERS_C 100000
#define N_NODES_C 150000
#define D 64
#define NB 2344              // ceil(150000/64) fine buckets (compact-row space)
#define NSUP 74              // ceil(150000/2048) super buckets
#define CPAD 16              // global cursor padding: 1 int per 64B line
#define SPAD 68              // transform transposed-tile row stride
#define BCAP 2048            // per-fine-bucket LDS sort capacity
#define S1CAP 2352           // S1 per-block chunk capacity (chunk ~2345)
#define S2CAP 2560           // S2 per-block chunk capacity (mean ~2100)
#define BPS 16               // blocks per super in S2

// ---------------- Needed-set marking ----------------
__global__ __launch_bounds__(256) void mark1_k(
    const int* __restrict__ u, const int* __restrict__ it,
    unsigned char* __restrict__ samp, unsigned char* __restrict__ need, int batch)
{
    int i = blockIdx.x * blockDim.x + threadIdx.x;
    if (i >= 2 * batch) return;
    int n = (i < batch) ? u[i] : N_USERS_C + it[i - batch];
    samp[n] = 1;
    need[n] = 1;
}

__global__ __launch_bounds__(256) void mark2_k(
    const int* __restrict__ rows, const int* __restrict__ cols,
    const unsigned char* __restrict__ samp, unsigned char* __restrict__ need, int nnz)
{
    int gtid = blockIdx.x * blockDim.x + threadIdx.x;
    int stride = gridDim.x * blockDim.x;
    for (int e = gtid; e < nnz; e += stride)
        if (samp[rows[e]]) need[cols[e]] = 1;
}

// ---------------- 3-kernel scan over need flags -> idx / list / M ----------------
__global__ __launch_bounds__(1024) void scan1_k(
    const unsigned char* __restrict__ need, int* __restrict__ part,
    int* __restrict__ bsum, int n)
{
    __shared__ int wsum[16];
    int i = blockIdx.x * 1024 + threadIdx.x;
    int lane = threadIdx.x & 63, wid = threadIdx.x >> 6;
    int v = (i < n) ? (int)need[i] : 0;
    int incl = v;
    #pragma unroll
    for (int off = 1; off < 64; off <<= 1) {
        int t = __shfl_up(incl, off);
        if (lane >= off) incl += t;
    }
    if (lane == 63) wsum[wid] = incl;
    __syncthreads();
    int woff = 0;
    for (int w = 0; w < wid; ++w) woff += wsum[w];
    if (i < n) part[i] = woff + incl - v;
    if (threadIdx.x == 1023) bsum[blockIdx.x] = woff + incl;
}

__global__ __launch_bounds__(1024) void scan2_k(
    int* __restrict__ bsum, int nb, int* __restrict__ Mptr)
{
    __shared__ int wsum[16];
    int lane = threadIdx.x & 63, wid = threadIdx.x >> 6;
    int i = threadIdx.x;
    int v = (i < nb) ? bsum[i] : 0;
    int incl = v;
    #pragma unroll
    for (int off = 1; off < 64; off <<= 1) {
        int t = __shfl_up(incl, off);
        if (lane >= off) incl += t;
    }
    if (lane == 63) wsum[wid] = incl;
    __syncthreads();
    int woff = 0;
    for (int w = 0; w < wid; ++w) woff += wsum[w];
    if (i < nb) bsum[i] = woff + incl - v;
    if (i == nb - 1) Mptr[0] = woff + incl;
}

// idx[n] = compact index if needed else -1 ; list[compact] = n
__global__ __launch_bounds__(256) void scan3_k(
    const int* __restrict__ bsum, int* __restrict__ idx,
    const unsigned char* __restrict__ need, int* __restrict__ list, int n)
{
    int i = blockIdx.x * blockDim.x + threadIdx.x;
    if (i >= n) return;
    int t = idx[i] + bsum[i >> 10];
    if (need[i]) { idx[i] = t; list[t] = i; }
    else idx[i] = -1;
}

// ---------------- Fused fine+super histogram over needed edges ----------------
__global__ __launch_bounds__(256) void histc_k(
    const int* __restrict__ rows, const int* __restrict__ idx,
    int* __restrict__ bcountP, int* __restrict__ scountP, int nnz)
{
    __shared__ int lh[NB];
    for (int i = threadIdx.x; i < NB; i += 256) lh[i] = 0;
    __syncthreads();
    int gtid = blockIdx.x * blockDim.x + threadIdx.x;
    int stride = gridDim.x * blockDim.x;
    for (int e = gtid; e < nnz; e += stride) {
        int ci = idx[rows[e]];
        if (ci >= 0) atomicAdd(&lh[ci >> 6], 1);
    }
    __syncthreads();
    for (int b = threadIdx.x; b < NB; b += 256) {
        int c = lh[b];
        if (c) atomicAdd(&bcountP[b * CPAD], c);
    }
    for (int sp = threadIdx.x; sp < NSUP; sp += 256) {
        int hi = min(sp * 32 + 32, NB);
        int c = 0;
        for (int b = sp * 32; b < hi; ++b) c += lh[b];
        if (c) atomicAdd(&scountP[sp * CPAD], c);
    }
}

// ---------------- Merged single-block: scan fine + super counts, init cursors ----------------
__global__ __launch_bounds__(1024) void scanall_k(
    const int* __restrict__ bcountP, const int* __restrict__ scountP,
    int* __restrict__ bstart, int* __restrict__ sstart,
    int* __restrict__ bcur, int* __restrict__ scur,
    int* __restrict__ rowptr, const int* __restrict__ Mptr)
{
    __shared__ int wsum[16];
    __shared__ int woff[16];
    __shared__ int carry;
    __shared__ int tile_total;
    int lane = threadIdx.x & 63;
    int wid  = threadIdx.x >> 6;

    // phase 1: fine buckets
    if (threadIdx.x == 0) carry = 0;
    __syncthreads();
    for (int base = 0; base < NB; base += 1024) {
        int i = base + (int)threadIdx.x;
        int v = (i < NB) ? bcountP[i * CPAD] : 0;
        int incl = v;
        #pragma unroll
        for (int off = 1; off < 64; off <<= 1) {
            int t = __shfl_up(incl, off);
            if (lane >= off) incl += t;
        }
        if (lane == 63) wsum[wid] = incl;
        __syncthreads();
        if (threadIdx.x == 0) {
            int run = 0;
            #pragma unroll
            for (int w = 0; w < 16; ++w) { int t = wsum[w]; woff[w] = run; run += t; }
            tile_total = run;
        }
        __syncthreads();
        if (i < NB) {
            int st = carry + woff[wid] + incl - v;
            bstart[i] = st;
            bcur[i * CPAD] = st;
        }
        __syncthreads();
        if (threadIdx.x == 0) carry += tile_total;
        __syncthreads();
    }
    if (threadIdx.x == 0) {
        bstart[NB] = carry;
        rowptr[Mptr[0]] = carry;
    }
    __syncthreads();

    // phase 2: super buckets (one tile)
    {
        int i = (int)threadIdx.x;
        int v = (i < NSUP) ? scountP[i * CPAD] : 0;
        int incl = v;
        #pragma unroll
        for (int off = 1; off < 64; off <<= 1) {
            int t = __shfl_up(incl, off);
            if (lane >= off) incl += t;
        }
        if (lane == 63) wsum[wid] = incl;
        __syncthreads();
        int woff2 = 0;
        for (int w = 0; w < wid; ++w) woff2 += wsum[w];
        if (i < NSUP) {
            int st = woff2 + incl - v;
            sstart[i] = st;
            scur[i * CPAD] = st;
        }
        if (i == NSUP - 1) sstart[NSUP] = woff2 + incl;
    }
}

// ---------------- S1: needed edges -> super-buckets (compact space) ----------------
__global__ __launch_bounds__(256) void s1_k(
    const int* __restrict__ rows, const int* __restrict__ cols,
    const float* __restrict__ vals, const int* __restrict__ idx,
    int* __restrict__ scurP, int2* __restrict__ pairs1, int nnz)
{
    __shared__ int2 sbuf[S1CAP];
    __shared__ unsigned char smap[S1CAP];
    __shared__ int lcnt[NSUP], lofs[NSUP], lcur[NSUP], gb[NSUP];
    __shared__ int stot;
    int t = threadIdx.x;
    for (int i = t; i < NSUP; i += 256) lcnt[i] = 0;
    __syncthreads();
    int per = (nnz + gridDim.x - 1) / gridDim.x;
    int s = blockIdx.x * per;
    int e = min(nnz, s + per);
    for (int i = s + t; i < e; i += 256) {
        int ci = idx[rows[i]];
        if (ci >= 0) atomicAdd(&lcnt[ci >> 11], 1);
    }
    __syncthreads();
    if (t == 0) {
        int run = 0;
        for (int i = 0; i < NSUP; ++i) { lofs[i] = run; run += lcnt[i]; }
        stot = run;
    }
    __syncthreads();
    for (int i = t; i < NSUP; i += 256) {
        int c = lcnt[i];
        gb[i] = c ? atomicAdd(&scurP[i * CPAD], c) : 0;
        lcur[i] = lofs[i];
    }
    __syncthreads();
    for (int i = s + t; i < e; i += 256) {
        int ci = idx[rows[i]];
        if (ci < 0) continue;
        int sp = ci >> 11;
        int dst = atomicAdd(&lcur[sp], 1);
        sbuf[dst] = make_int2(((ci & 2047) << 18) | cols[i], __float_as_int(vals[i]));
        smap[dst] = (unsigned char)sp;
    }
    __syncthreads();
    int m = stot;
    for (int i = t; i < m; i += 256) {
        int sp = smap[i];
        pairs1[gb[sp] + (i - lofs[sp])] = sbuf[i];
    }
}

// ---------------- S2: supers -> 64-row fine buckets ----------------
__global__ __launch_bounds__(256) void s2_k(
    const int* __restrict__ sstart, const int2* __restrict__ pairs1,
    int* __restrict__ bcurP, int2* __restrict__ pairs)
{
    __shared__ int2 sbuf[S2CAP];
    __shared__ unsigned char fmap[S2CAP];
    __shared__ int fcnt[32], fofs[32], fcur[32], gb[32];
    int sp = blockIdx.x / BPS, part = blockIdx.x % BPS;
    int lo = sstart[sp], hi = sstart[sp + 1];
    int len = hi - lo;
    int per = (len + BPS - 1) / BPS;
    int cs = lo + part * per;
    int ce = min(hi, cs + per);
    int m = ce - cs;
    if (m <= 0) return;
    int t = threadIdx.x;
    if (t < 32) fcnt[t] = 0;
    __syncthreads();
    for (int i = t; i < m; i += 256)
        atomicAdd(&fcnt[(pairs1[cs + i].x >> 18) >> 6], 1);
    __syncthreads();
    if (t < 32) {
        int v = fcnt[t], incl = v;
        #pragma unroll
        for (int o = 1; o < 32; o <<= 1) {
            int u = __shfl_up(incl, o);
            if (t >= o) incl += u;
        }
        fofs[t] = incl - v;
        fcur[t] = incl - v;
        gb[t] = v ? atomicAdd(&bcurP[(sp * 32 + t) * CPAD], v) : 0;
    }
    __syncthreads();
    for (int i = t; i < m; i += 256) {
        int2 p = pairs1[cs + i];
        int ris = p.x >> 18;
        int f = ris >> 6;
        int dst = atomicAdd(&fcur[f], 1);
        sbuf[dst] = make_int2(((ris & 63) << 18) | (p.x & 0x3FFFF), p.y);
        fmap[dst] = (unsigned char)f;
    }
    __syncthreads();
    for (int i = t; i < m; i += 256) {
        int f = fmap[i];
        pairs[gb[f] + (i - fofs[f])] = sbuf[i];
    }
}

// ---------------- Per-bucket LDS counting sort -> exact CSR ----------------
// Direct global scatter on write-out: the ~8KB bucket window is L2-dirty from
// s2, so scattered 8B stores merge in L2 (no obuf -> 17KB LDS, 9 blocks/CU).
__global__ __launch_bounds__(256) void sortb_k(
    const int* __restrict__ bstart, int2* __restrict__ pairs,
    int* __restrict__ rowptr, const int* __restrict__ Mptr)
{
    __shared__ int2 buf[BCAP];
    __shared__ int cnt[64];
    __shared__ int cur[64];
    int b = blockIdx.x;
    int s = bstart[b], e = bstart[b + 1];
    int m = e - s;
    int t = threadIdx.x;
    int M = Mptr[0];
    if (t < 64) cnt[t] = 0;
    __syncthreads();
    for (int i = t; i < m; i += 256) {
        int2 p = pairs[s + i];
        buf[i] = p;
        atomicAdd(&cnt[p.x >> 18], 1);
    }
    __syncthreads();
    if (t < 64) {
        int v = cnt[t];
        int incl = v;
        #pragma unroll
        for (int o = 1; o < 64; o <<= 1) {
            int u = __shfl_up(incl, o);
            if (t >= o) incl += u;
        }
        cur[t] = incl - v;
        int n = (b << 6) + t;
        if (n < M) rowptr[n] = s + incl - v;
    }
    __syncthreads();
    for (int i = t; i < m; i += 256) {
        int2 p = buf[i];
        int dst = atomicAdd(&cur[p.x >> 18], 1);
        pairs[s + dst] = make_int2(p.x & 0x3FFFF, p.y);
    }
}

// ---------------- Layer-1 gather: one wave per needed (compact) row ----------------
__global__ __launch_bounds__(256) void gather1_k(
    const int* __restrict__ rowptr, const int2* __restrict__ pairs,
    const float* __restrict__ x, float* __restrict__ side,
    const int* __restrict__ Mptr)
{
    int gtid = blockIdx.x * blockDim.x + threadIdx.x;
    int wave = gtid >> 6;
    int lane = threadIdx.x & 63;
    if (wave >= Mptr[0]) return;
    int s  = rowptr[wave];
    int ep = rowptr[wave + 1];

    float acc = 0.0f;
    for (int base = s; base < ep; base += 64) {
        int2 p = make_int2(0, 0);
        if (base + lane < ep) p = pairs[base + lane];
        int cnt4 = (min(ep - base, 64) + 3) & ~3;
        for (int j = 0; j < cnt4; j += 4) {
            int c0 = __shfl(p.x, j + 0);
            int c1 = __shfl(p.x, j + 1);
            int c2 = __shfl(p.x, j + 2);
            int c3 = __shfl(p.x, j + 3);
            float v0 = __int_as_float(__shfl(p.y, j + 0));
            float v1 = __int_as_float(__shfl(p.y, j + 1));
            float v2 = __int_as_float(__shfl(p.y, j + 2));
            float v3 = __int_as_float(__shfl(p.y, j + 3));
            float f0 = x[(size_t)c0 * D + lane];
            float f1 = x[(size_t)c1 * D + lane];
            float f2 = x[(size_t)c2 * D + lane];
            float f3 = x[(size_t)c3 * D + lane];
            acc = fmaf(v0, f0, acc);
            acc = fmaf(v1, f1, acc);
            acc = fmaf(v2, f2, acc);
            acc = fmaf(v3, f3, acc);
        }
    }
    side[(size_t)wave * D + lane] = acc;
}

// ---------------- Layer-2 gather (sampled): e1 via compact idx ----------------
__global__ __launch_bounds__(256) void gather2_k(
    const int* __restrict__ rowptr, const int2* __restrict__ pairs,
    const float* __restrict__ e1c, const int* __restrict__ idx,
    float* __restrict__ side2c, float* __restrict__ egoc,
    const int* __restrict__ u, const int* __restrict__ it, int batch)
{
    int gtid = blockIdx.x * blockDim.x + threadIdx.x;
    int wave = gtid >> 6;
    int lane = threadIdx.x & 63;
    if (wave >= 2 * batch) return;
    int n = (wave < batch) ? u[wave] : N_USERS_C + it[wave - batch];
    int cr = idx[n];
    int s  = rowptr[cr];
    int ep = rowptr[cr + 1];

    float acc = 0.0f;
    for (int base = s; base < ep; base += 64) {
        int2 p = make_int2(0, 0);
        if (base + lane < ep) p = pairs[base + lane];
        int cnt = min(ep - base, 64);
        for (int j = 0; j < cnt; ++j) {
            int   c = __shfl(p.x, j);
            float v = __int_as_float(__shfl(p.y, j));
            acc = fmaf(v, e1c[(size_t)idx[c] * D + lane], acc);
        }
    }
    side2c[(size_t)wave * D + lane] = acc;
    egoc[(size_t)wave * D + lane] = e1c[(size_t)cr * D + lane];
}

// ---------------- Tiled transform ----------------
__global__ __launch_bounds__(256) void transform_k(
    const float* __restrict__ S, const float* __restrict__ Eb,
    const float* __restrict__ Wg, const float* __restrict__ bg,
    const float* __restrict__ Wb, const float* __restrict__ bb,
    float* __restrict__ out, const int* __restrict__ list,
    const int* __restrict__ Mptr, int nrows)
{
    __shared__ __align__(16) float sWg[D * D];
    __shared__ __align__(16) float sWb[D * D];
    __shared__ __align__(16) float sAT[D][SPAD];
    __shared__ __align__(16) float sBT[D][SPAD];

    int nr = Mptr ? Mptr[0] : nrows;
    int t  = threadIdx.x;
    int tc = t & 15;
    int tr = t >> 4;
    int r0 = blockIdx.x * 64;
    if (r0 >= nr) return;

    for (int i = t; i < D * D; i += 256) {
        sWg[i] = Wg[i];
        sWb[i] = Wb[i];
    }
    for (int itr = 0; itr < 4; ++itr) {
        int rr  = itr * 16 + (t >> 4);
        int row = r0 + rr;
        float4 sv = make_float4(0.f, 0.f, 0.f, 0.f);
        float4 ev = sv;
        if (row < nr) {
            sv = *(const float4*)&S[(size_t)row * D + tc * 4];
            int er = list ? list[row] : row;
            ev = *(const float4*)&Eb[(size_t)er * D + tc * 4];
        }
        sAT[tc * 4 + 0][rr] = sv.x;
        sAT[tc * 4 + 1][rr] = sv.y;
        sAT[tc * 4 + 2][rr] = sv.z;
        sAT[tc * 4 + 3][rr] = sv.w;
        sBT[tc * 4 + 0][rr] = sv.x * ev.x;
        sBT[tc * 4 + 1][rr] = sv.y * ev.y;
        sBT[tc * 4 + 2][rr] = sv.z * ev.z;
        sBT[tc * 4 + 3][rr] = sv.w * ev.w;
    }
    __syncthreads();

    float acc[4][4] = {};
    for (int k = 0; k < D; ++k) {
        float4 a4 = *(const float4*)&sAT[k][tr * 4];
        float4 b4 = *(const float4*)&sBT[k][tr * 4];
        float4 g4 = *(const float4*)&sWg[k * D + tc * 4];
        float4 w4 = *(const float4*)&sWb[k * D + tc * 4];
        float av[4] = {a4.x, a4.y, a4.z, a4.w};
        float bv[4] = {b4.x, b4.y, b4.z, b4.w};
        float gv[4] = {g4.x, g4.y, g4.z, g4.w};
        float wv[4] = {w4.x, w4.y, w4.z, w4.w};
        #pragma unroll
        for (int i = 0; i < 4; ++i)
            #pragma unroll
            for (int j = 0; j < 4; ++j)
                acc[i][j] = fmaf(av[i], gv[j], fmaf(bv[i], wv[j], acc[i][j]));
    }

    float4 bgv = *(const float4*)&bg[tc * 4];
    float4 bbv = *(const float4*)&bb[tc * 4];
    float bias[4] = {bgv.x + bbv.x, bgv.y + bbv.y, bgv.z + bbv.z, bgv.w + bbv.w};

    float vv[4][4];
    float ss[4] = {0.f, 0.f, 0.f, 0.f};
    #pragma unroll
    for (int i = 0; i < 4; ++i) {
        #pragma unroll
        for (int j = 0; j < 4; ++j) {
            float v = acc[i][j] + bias[j];
            v = (v > 0.0f) ? v : 0.2f * v;
            vv[i][j] = v;
            ss[i] += v * v;
        }
    }
    #pragma unroll
    for (int i = 0; i < 4; ++i) {
        #pragma unroll
        for (int off = 1; off < 16; off <<= 1)
            ss[i] += __shfl_xor(ss[i], off);
    }
    #pragma unroll
    for (int i = 0; i < 4; ++i) {
        int row = r0 + tr * 4 + i;
        if (row < nr) {
            float inv = 1.0f / fmaxf(sqrtf(ss[i]), 1e-12f);
            float4 o = make_float4(vv[i][0] * inv, vv[i][1] * inv,
                                   vv[i][2] * inv, vv[i][3] * inv);
            *(float4*)&out[(size_t)row * D + tc * 4] = o;
        }
    }
}

// ---------------- Readout ----------------
__global__ __launch_bounds__(256) void gamma_k(
    const float* __restrict__ x, const float* __restrict__ e1c,
    const int* __restrict__ idx, const float* __restrict__ e2c,
    const int* __restrict__ users, const int* __restrict__ items,
    float* __restrict__ gamma, int batch)
{
    int gtid = blockIdx.x * blockDim.x + threadIdx.x;
    int wave = gtid >> 6;
    int lane = threadIdx.x & 63;
    if (wave >= batch) return;
    size_t uu = (size_t)users[wave];
    size_t tt = (size_t)(N_USERS_C + items[wave]);
    float acc = x[uu * D + lane] * x[tt * D + lane]
              + e1c[(size_t)idx[uu] * D + lane] * e1c[(size_t)idx[tt] * D + lane]
              + e2c[(size_t)wave * D + lane] * e2c[(size_t)(batch + wave) * D + lane];
    #pragma unroll
    for (int off = 1; off < 64; off <<= 1) acc += __shfl_xor(acc, off);
    if (lane == 0) gamma[wave] = acc;
}

extern "C" void kernel_launch(void* const* d_in, const int* in_sizes, int n_in,
                              void* d_out, int out_size, void* d_ws, size_t ws_size,
                              hipStream_t stream) {
    const int*   rows  = (const int*)d_in[0];
    const int*   cols  = (const int*)d_in[1];
    const float* vals  = (const float*)d_in[2];
    const float* x     = (const float*)d_in[3];
    const int*   users = (const int*)d_in[4];
    const int*   items = (const int*)d_in[5];
    const float* Wg0 = (const float*)d_in[6];
    const float* bg0 = (const float*)d_in[7];
    const float* Wb0 = (const float*)d_in[8];
    const float* bb0 = (const float*)d_in[9];
    const float* Wg1 = (const float*)d_in[10];
    const float* bg1 = (const float*)d_in[11];
    const float* Wb1 = (const float*)d_in[12];
    const float* bb1 = (const float*)d_in[13];

    int nnz   = in_sizes[0];
    int batch = in_sizes[4];
    float* out = (float*)d_out;

    size_t emb = (size_t)N_NODES_C * D;
    float* A       = (float*)d_ws;                 // e1c [M x 64]
    float* Sbuf    = A + emb;                      // side_c; aliases pairs1 / layer2 compacts
    int*   bstart  = (int*)(Sbuf + emb);           // NB+1 (+pad)
    int*   sstart  = bstart + (NB + 2);            // NSUP+1 (+pad)
    int*   bcountP = sstart + (NSUP + 2);
    int*   scountP = bcountP + NB * CPAD;          // contiguous with bcountP
    int*   bcur    = scountP + NSUP * CPAD;
    int*   scur    = bcur + NB * CPAD;
    int*   rowptr  = scur + NSUP * CPAD;           // M+1 (alloc N+2)
    int*   idx     = rowptr + N_NODES_C + 2;       // [N]
    int*   list    = idx + N_NODES_C;              // [N]
    int*   bsum    = list + N_NODES_C;             // [1024]
    int*   Mptr    = bsum + 1024;                  // [4]
    unsigned char* need = (unsigned char*)(Mptr + 4);        // [N]
    unsigned char* samp = need + N_NODES_C;                  // [N]
    int2*  pairs   = (int2*)(((size_t)(samp + N_NODES_C) + 15) & ~(size_t)15);

    int2*  pairs1 = (int2*)Sbuf;                   // build-time only
    float* side2c = Sbuf;                          // layer-2 compacts (after transform1)
    float* egoc   = Sbuf + (size_t)2 * 2048 * D;
    float* e2c    = egoc + (size_t)2 * 2048 * D;

    int nscan = (N_NODES_C + 1023) / 1024;         // 147

    // --- needed-set mark + compact ---
    hipMemsetAsync(bcountP, 0, (NB + NSUP) * CPAD * sizeof(int), stream);
    hipMemsetAsync(need, 0, 2 * N_NODES_C, stream);
    mark1_k<<<(2 * batch + 255) / 256, 256, 0, stream>>>(users, items, samp, need, batch);
    mark2_k<<<1024, 256, 0, stream>>>(rows, cols, samp, need, nnz);
    scan1_k<<<nscan, 1024, 0, stream>>>(need, idx, bsum, N_NODES_C);
    scan2_k<<<1, 1024, 0, stream>>>(bsum, nscan, Mptr);
    scan3_k<<<(N_NODES_C + 255) / 256, 256, 0, stream>>>(bsum, idx, need, list, N_NODES_C);

    // --- two-level bucket build over needed edges (compact row space) ---
    histc_k<<<1024, 256, 0, stream>>>(rows, idx, bcountP, scountP, nnz);
    scanall_k<<<1, 1024, 0, stream>>>(bcountP, scountP, bstart, sstart,
                                      bcur, scur, rowptr, Mptr);
    int g1 = (nnz + 2343) / 2344;                  // chunk <= S1CAP
    s1_k<<<g1, 256, 0, stream>>>(rows, cols, vals, idx, scur, pairs1, nnz);
    s2_k<<<NSUP * BPS, 256, 0, stream>>>(sstart, pairs1, bcur, pairs);
    sortb_k<<<NB, 256, 0, stream>>>(bstart, pairs, rowptr, Mptr);

    // --- Layer 1 over M needed rows (worst-case grid, early exit on M) ---
    gather1_k<<<(N_NODES_C * 64 + 255) / 256, 256, 0, stream>>>(
        rowptr, pairs, x, Sbuf, Mptr);
    transform_k<<<(N_NODES_C + 63) / 64, 256, 0, stream>>>(
        Sbuf, x, Wg0, bg0, Wb0, bb0, A, list, Mptr, 0);

    // --- Layer 2 (sampled 2*batch rows) ---
    gather2_k<<<(2 * batch * 64 + 255) / 256, 256, 0, stream>>>(
        rowptr, pairs, A, idx, side2c, egoc, users, items, batch);
    transform_k<<<(2 * batch + 63) / 64, 256, 0, stream>>>(
        side2c, egoc, Wg1, bg1, Wb1, bb1, e2c, nullptr, nullptr, 2 * batch);

    // --- Readout ---
    gamma_k<<<(batch * 64 + 255) / 256, 256, 0, stream>>>(
        x, A, idx, e2c, users, items, out, batch);
}

// Round 9
// 296.526 us; speedup vs baseline: 1.2193x; 1.2193x over previous
//
#include <hip/hip_runtime.h>

#define N_USERS_C 100000
#define N_NODES_C 150000
#define D 64
#define NB 2344              // ceil(150000/64) fine buckets (compact-row space)
#define NSUP 74              // ceil(150000/2048) super buckets
#define CPAD 16              // global cursor padding: 1 int per 64B line
#define SPAD 68              // transform transposed-tile row stride
#define FCAP 1536            // fixed fine-bucket capacity (mean ~1030, sigma ~32)
#define SCAP 36864           // fixed super-bucket capacity (mean ~33k, sigma ~181)
#define S1CAP 2352           // S1 per-block chunk capacity (chunk ~2344)
#define S2CAP 2560           // S2 per-block chunk capacity (<= ceil(SCAP/BPS))
#define BPS 16               // blocks per super in S2

// ---------------- Needed-set marking ----------------
__global__ __launch_bounds__(256) void mark1_k(
    const int* __restrict__ u, const int* __restrict__ it,
    unsigned char* __restrict__ samp, unsigned char* __restrict__ need, int batch)
{
    int i = blockIdx.x * blockDim.x + threadIdx.x;
    if (i >= 2 * batch) return;
    int n = (i < batch) ? u[i] : N_USERS_C + it[i - batch];
    samp[n] = 1;
    need[n] = 1;
}

__global__ __launch_bounds__(256) void mark2_k(
    const int* __restrict__ rows, const int* __restrict__ cols,
    const unsigned char* __restrict__ samp, unsigned char* __restrict__ need, int nnz)
{
    int gtid = blockIdx.x * blockDim.x + threadIdx.x;
    int stride = gridDim.x * blockDim.x;
    for (int e = gtid; e < nnz; e += stride)
        if (samp[rows[e]]) need[cols[e]] = 1;
}

// ---------------- 3-kernel scan over need flags -> idx / list / M ----------------
__global__ __launch_bounds__(1024) void scan1_k(
    const unsigned char* __restrict__ need, int* __restrict__ part,
    int* __restrict__ bsum, int n)
{
    __shared__ int wsum[16];
    int i = blockIdx.x * 1024 + threadIdx.x;
    int lane = threadIdx.x & 63, wid = threadIdx.x >> 6;
    int v = (i < n) ? (int)need[i] : 0;
    int incl = v;
    #pragma unroll
    for (int off = 1; off < 64; off <<= 1) {
        int t = __shfl_up(incl, off);
        if (lane >= off) incl += t;
    }
    if (lane == 63) wsum[wid] = incl;
    __syncthreads();
    int woff = 0;
    for (int w = 0; w < wid; ++w) woff += wsum[w];
    if (i < n) part[i] = woff + incl - v;
    if (threadIdx.x == 1023) bsum[blockIdx.x] = woff + incl;
}

__global__ __launch_bounds__(1024) void scan2_k(
    int* __restrict__ bsum, int nb, int* __restrict__ Mptr)
{
    __shared__ int wsum[16];
    int lane = threadIdx.x & 63, wid = threadIdx.x >> 6;
    int i = threadIdx.x;
    int v = (i < nb) ? bsum[i] : 0;
    int incl = v;
    #pragma unroll
    for (int off = 1; off < 64; off <<= 1) {
        int t = __shfl_up(incl, off);
        if (lane >= off) incl += t;
    }
    if (lane == 63) wsum[wid] = incl;
    __syncthreads();
    int woff = 0;
    for (int w = 0; w < wid; ++w) woff += wsum[w];
    if (i < nb) bsum[i] = woff + incl - v;
    if (i == nb - 1) Mptr[0] = woff + incl;
}

// idx[n] = compact index if needed else -1 ; list[compact] = n
__global__ __launch_bounds__(256) void scan3_k(
    const int* __restrict__ bsum, int* __restrict__ idx,
    const unsigned char* __restrict__ need, int* __restrict__ list, int n)
{
    int i = blockIdx.x * blockDim.x + threadIdx.x;
    if (i >= n) return;
    int t = idx[i] + bsum[i >> 10];
    if (need[i]) { idx[i] = t; list[t] = i; }
    else idx[i] = -1;
}

// ---------------- Cursor init: fixed-capacity bucket bases ----------------
__global__ __launch_bounds__(256) void initcur_k(
    int* __restrict__ bcur, int* __restrict__ scur)
{
    int i = blockIdx.x * blockDim.x + threadIdx.x;
    if (i < NB) bcur[i * CPAD] = i * FCAP;
    if (i < NSUP) scur[i * CPAD] = i * SCAP;
}

// ---------------- S1: needed edges -> fixed-cap super-buckets (compact space) ----------------
// pairs1[p].x = ((crow & 2047) << 18) | col ; super = crow >> 11.
__global__ __launch_bounds__(256) void s1_k(
    const int* __restrict__ rows, const int* __restrict__ cols,
    const float* __restrict__ vals, const int* __restrict__ idx,
    int* __restrict__ scurP, int2* __restrict__ pairs1, int nnz)
{
    __shared__ int2 sbuf[S1CAP];
    __shared__ unsigned char smap[S1CAP];
    __shared__ int lcnt[NSUP], lofs[NSUP], lcur[NSUP], gb[NSUP];
    __shared__ int stot;
    int t = threadIdx.x;
    for (int i = t; i < NSUP; i += 256) lcnt[i] = 0;
    __syncthreads();
    int per = (nnz + gridDim.x - 1) / gridDim.x;
    int s = blockIdx.x * per;
    int e = min(nnz, s + per);
    for (int i = s + t; i < e; i += 256) {
        int ci = idx[rows[i]];
        if (ci >= 0) atomicAdd(&lcnt[ci >> 11], 1);
    }
    __syncthreads();
    if (t == 0) {
        int run = 0;
        for (int i = 0; i < NSUP; ++i) { lofs[i] = run; run += lcnt[i]; }
        stot = run;
    }
    __syncthreads();
    for (int i = t; i < NSUP; i += 256) {
        int c = lcnt[i];
        gb[i] = c ? atomicAdd(&scurP[i * CPAD], c) : 0;
        lcur[i] = lofs[i];
    }
    __syncthreads();
    for (int i = s + t; i < e; i += 256) {
        int ci = idx[rows[i]];
        if (ci < 0) continue;
        int sp = ci >> 11;
        int dst = atomicAdd(&lcur[sp], 1);
        sbuf[dst] = make_int2(((ci & 2047) << 18) | cols[i], __float_as_int(vals[i]));
        smap[dst] = (unsigned char)sp;
    }
    __syncthreads();
    int m = stot;
    for (int i = t; i < m; i += 256) {
        int sp = smap[i];
        pairs1[gb[sp] + (i - lofs[sp])] = sbuf[i];
    }
}

// ---------------- S2: supers -> fixed-cap 64-row fine buckets ----------------
__global__ __launch_bounds__(256) void s2_k(
    const int* __restrict__ scurP, const int2* __restrict__ pairs1,
    int* __restrict__ bcurP, int2* __restrict__ pairs)
{
    __shared__ int2 sbuf[S2CAP];
    __shared__ unsigned char fmap[S2CAP];
    __shared__ int fcnt[32], fofs[32], fcur[32], gb[32];
    int sp = blockIdx.x / BPS, part = blockIdx.x % BPS;
    int lo = sp * SCAP, hi = scurP[sp * CPAD];
    int len = hi - lo;
    if (len <= 0) return;
    int per = (len + BPS - 1) / BPS;
    int cs = lo + part * per;
    int ce = min(hi, cs + per);
    int m = ce - cs;
    if (m <= 0) return;
    int t = threadIdx.x;
    if (t < 32) fcnt[t] = 0;
    __syncthreads();
    for (int i = t; i < m; i += 256)
        atomicAdd(&fcnt[(pairs1[cs + i].x >> 18) >> 6], 1);
    __syncthreads();
    if (t < 32) {
        int v = fcnt[t], incl = v;
        #pragma unroll
        for (int o = 1; o < 32; o <<= 1) {
            int u = __shfl_up(incl, o);
            if (t >= o) incl += u;
        }
        fofs[t] = incl - v;
        fcur[t] = incl - v;
        gb[t] = v ? atomicAdd(&bcurP[(sp * 32 + t) * CPAD], v) : 0;
    }
    __syncthreads();
    for (int i = t; i < m; i += 256) {
        int2 p = pairs1[cs + i];
        int ris = p.x >> 18;
        int f = ris >> 6;
        int dst = atomicAdd(&fcur[f], 1);
        sbuf[dst] = make_int2(((ris & 63) << 18) | (p.x & 0x3FFFF), p.y);
        fmap[dst] = (unsigned char)f;
    }
    __syncthreads();
    for (int i = t; i < m; i += 256) {
        int f = fmap[i];
        pairs[gb[f] + (i - fofs[f])] = sbuf[i];
    }
}

// ---------------- Per-bucket LDS counting sort -> per-row ranges ----------------
// rp[b*65 + j] = start of row j in bucket b; rp[b*65 + 64] = bucket end.
__global__ __launch_bounds__(256) void sortb_k(
    const int* __restrict__ bcurP, int2* __restrict__ pairs,
    int* __restrict__ rp)
{
    __shared__ int2 buf[FCAP];
    __shared__ int cnt[64];
    __shared__ int cur[64];
    int b = blockIdx.x;
    int s = b * FCAP;
    int e = bcurP[b * CPAD];
    int m = e - s;
    int t = threadIdx.x;
    if (t < 64) cnt[t] = 0;
    __syncthreads();
    for (int i = t; i < m; i += 256) {
        int2 p = pairs[s + i];
        buf[i] = p;
        atomicAdd(&cnt[p.x >> 18], 1);
    }
    __syncthreads();
    if (t < 64) {
        int v = cnt[t];
        int incl = v;
        #pragma unroll
        for (int o = 1; o < 64; o <<= 1) {
            int u = __shfl_up(incl, o);
            if (t >= o) incl += u;
        }
        cur[t] = incl - v;
        rp[b * 65 + t] = s + incl - v;
        if (t == 63) rp[b * 65 + 64] = s + incl;
    }
    __syncthreads();
    for (int i = t; i < m; i += 256) {
        int2 p = buf[i];
        int dst = atomicAdd(&cur[p.x >> 18], 1);
        pairs[s + dst] = make_int2(p.x & 0x3FFFF, p.y);
    }
}

// ---------------- Layer-1 gather: one wave per needed (compact) row ----------------
__global__ __launch_bounds__(256) void gather1_k(
    const int* __restrict__ rp, const int2* __restrict__ pairs,
    const float* __restrict__ x, float* __restrict__ side,
    const int* __restrict__ Mptr)
{
    int gtid = blockIdx.x * blockDim.x + threadIdx.x;
    int wave = gtid >> 6;
    int lane = threadIdx.x & 63;
    if (wave >= Mptr[0]) return;
    int rb = (wave >> 6) * 65 + (wave & 63);
    int s  = rp[rb];
    int ep = rp[rb + 1];

    float acc = 0.0f;
    for (int base = s; base < ep; base += 64) {
        int2 p = make_int2(0, 0);
        if (base + lane < ep) p = pairs[base + lane];
        int cnt4 = (min(ep - base, 64) + 3) & ~3;
        for (int j = 0; j < cnt4; j += 4) {
            int c0 = __shfl(p.x, j + 0);
            int c1 = __shfl(p.x, j + 1);
            int c2 = __shfl(p.x, j + 2);
            int c3 = __shfl(p.x, j + 3);
            float v0 = __int_as_float(__shfl(p.y, j + 0));
            float v1 = __int_as_float(__shfl(p.y, j + 1));
            float v2 = __int_as_float(__shfl(p.y, j + 2));
            float v3 = __int_as_float(__shfl(p.y, j + 3));
            float f0 = x[(size_t)c0 * D + lane];
            float f1 = x[(size_t)c1 * D + lane];
            float f2 = x[(size_t)c2 * D + lane];
            float f3 = x[(size_t)c3 * D + lane];
            acc = fmaf(v0, f0, acc);
            acc = fmaf(v1, f1, acc);
            acc = fmaf(v2, f2, acc);
            acc = fmaf(v3, f3, acc);
        }
    }
    side[(size_t)wave * D + lane] = acc;
}

// ---------------- Layer-2 gather (sampled): e1 via compact idx ----------------
__global__ __launch_bounds__(256) void gather2_k(
    const int* __restrict__ rp, const int2* __restrict__ pairs,
    const float* __restrict__ e1c, const int* __restrict__ idx,
    float* __restrict__ side2c, float* __restrict__ egoc,
    const int* __restrict__ u, const int* __restrict__ it, int batch)
{
    int gtid = blockIdx.x * blockDim.x + threadIdx.x;
    int wave = gtid >> 6;
    int lane = threadIdx.x & 63;
    if (wave >= 2 * batch) return;
    int n = (wave < batch) ? u[wave] : N_USERS_C + it[wave - batch];
    int cr = idx[n];
    int rb = (cr >> 6) * 65 + (cr & 63);
    int s  = rp[rb];
    int ep = rp[rb + 1];

    float acc = 0.0f;
    for (int base = s; base < ep; base += 64) {
        int2 p = make_int2(0, 0);
        if (base + lane < ep) p = pairs[base + lane];
        int cnt = min(ep - base, 64);
        for (int j = 0; j < cnt; ++j) {
            int   c = __shfl(p.x, j);
            float v = __int_as_float(__shfl(p.y, j));
            acc = fmaf(v, e1c[(size_t)idx[c] * D + lane], acc);
        }
    }
    side2c[(size_t)wave * D + lane] = acc;
    egoc[(size_t)wave * D + lane] = e1c[(size_t)cr * D + lane];
}

// ---------------- Tiled transform ----------------
__global__ __launch_bounds__(256) void transform_k(
    const float* __restrict__ S, const float* __restrict__ Eb,
    const float* __restrict__ Wg, const float* __restrict__ bg,
    const float* __restrict__ Wb, const float* __restrict__ bb,
    float* __restrict__ out, const int* __restrict__ list,
    const int* __restrict__ Mptr, int nrows)
{
    __shared__ __align__(16) float sWg[D * D];
    __shared__ __align__(16) float sWb[D * D];
    __shared__ __align__(16) float sAT[D][SPAD];
    __shared__ __align__(16) float sBT[D][SPAD];

    int nr = Mptr ? Mptr[0] : nrows;
    int t  = threadIdx.x;
    int tc = t & 15;
    int tr = t >> 4;
    int r0 = blockIdx.x * 64;
    if (r0 >= nr) return;

    for (int i = t; i < D * D; i += 256) {
        sWg[i] = Wg[i];
        sWb[i] = Wb[i];
    }
    for (int itr = 0; itr < 4; ++itr) {
        int rr  = itr * 16 + (t >> 4);
        int row = r0 + rr;
        float4 sv = make_float4(0.f, 0.f, 0.f, 0.f);
        float4 ev = sv;
        if (row < nr) {
            sv = *(const float4*)&S[(size_t)row * D + tc * 4];
            int er = list ? list[row] : row;
            ev = *(const float4*)&Eb[(size_t)er * D + tc * 4];
        }
        sAT[tc * 4 + 0][rr] = sv.x;
        sAT[tc * 4 + 1][rr] = sv.y;
        sAT[tc * 4 + 2][rr] = sv.z;
        sAT[tc * 4 + 3][rr] = sv.w;
        sBT[tc * 4 + 0][rr] = sv.x * ev.x;
        sBT[tc * 4 + 1][rr] = sv.y * ev.y;
        sBT[tc * 4 + 2][rr] = sv.z * ev.z;
        sBT[tc * 4 + 3][rr] = sv.w * ev.w;
    }
    __syncthreads();

    float acc[4][4] = {};
    for (int k = 0; k < D; ++k) {
        float4 a4 = *(const float4*)&sAT[k][tr * 4];
        float4 b4 = *(const float4*)&sBT[k][tr * 4];
        float4 g4 = *(const float4*)&sWg[k * D + tc * 4];
        float4 w4 = *(const float4*)&sWb[k * D + tc * 4];
        float av[4] = {a4.x, a4.y, a4.z, a4.w};
        float bv[4] = {b4.x, b4.y, b4.z, b4.w};
        float gv[4] = {g4.x, g4.y, g4.z, g4.w};
        float wv[4] = {w4.x, w4.y, w4.z, w4.w};
        #pragma unroll
        for (int i = 0; i < 4; ++i)
            #pragma unroll
            for (int j = 0; j < 4; ++j)
                acc[i][j] = fmaf(av[i], gv[j], fmaf(bv[i], wv[j], acc[i][j]));
    }

    float4 bgv = *(const float4*)&bg[tc * 4];
    float4 bbv = *(const float4*)&bb[tc * 4];
    float bias[4] = {bgv.x + bbv.x, bgv.y + bbv.y, bgv.z + bbv.z, bgv.w + bbv.w};

    float vv[4][4];
    float ss[4] = {0.f, 0.f, 0.f, 0.f};
    #pragma unroll
    for (int i = 0; i < 4; ++i) {
        #pragma unroll
        for (int j = 0; j < 4; ++j) {
            float v = acc[i][j] + bias[j];
            v = (v > 0.0f) ? v : 0.2f * v;
            vv[i][j] = v;
            ss[i] += v * v;
        }
    }
    #pragma unroll
    for (int i = 0; i < 4; ++i) {
        #pragma unroll
        for (int off = 1; off < 16; off <<= 1)
            ss[i] += __shfl_xor(ss[i], off);
    }
    #pragma unroll
    for (int i = 0; i < 4; ++i) {
        int row = r0 + tr * 4 + i;
        if (row < nr) {
            float inv = 1.0f / fmaxf(sqrtf(ss[i]), 1e-12f);
            float4 o = make_float4(vv[i][0] * inv, vv[i][1] * inv,
                                   vv[i][2] * inv, vv[i][3] * inv);
            *(float4*)&out[(size_t)row * D + tc * 4] = o;
        }
    }
}

// ---------------- Readout ----------------
__global__ __launch_bounds__(256) void gamma_k(
    const float* __restrict__ x, const float* __restrict__ e1c,
    const int* __restrict__ idx, const float* __restrict__ e2c,
    const int* __restrict__ users, const int* __restrict__ items,
    float* __restrict__ gamma, int batch)
{
    int gtid = blockIdx.x * blockDim.x + threadIdx.x;
    int wave = gtid >> 6;
    int lane = threadIdx.x & 63;
    if (wave >= batch) return;
    size_t uu = (size_t)users[wave];
    size_t tt = (size_t)(N_USERS_C + items[wave]);
    float acc = x[uu * D + lane] * x[tt * D + lane]
              + e1c[(size_t)idx[uu] * D + lane] * e1c[(size_t)idx[tt] * D + lane]
              + e2c[(size_t)wave * D + lane] * e2c[(size_t)(batch + wave) * D + lane];
    #pragma unroll
    for (int off = 1; off < 64; off <<= 1) acc += __shfl_xor(acc, off);
    if (lane == 0) gamma[wave] = acc;
}

extern "C" void kernel_launch(void* const* d_in, const int* in_sizes, int n_in,
                              void* d_out, int out_size, void* d_ws, size_t ws_size,
                              hipStream_t stream) {
    const int*   rows  = (const int*)d_in[0];
    const int*   cols  = (const int*)d_in[1];
    const float* vals  = (const float*)d_in[2];
    const float* x     = (const float*)d_in[3];
    const int*   users = (const int*)d_in[4];
    const int*   items = (const int*)d_in[5];
    const float* Wg0 = (const float*)d_in[6];
    const float* bg0 = (const float*)d_in[7];
    const float* Wb0 = (const float*)d_in[8];
    const float* bb0 = (const float*)d_in[9];
    const float* Wg1 = (const float*)d_in[10];
    const float* bg1 = (const float*)d_in[11];
    const float* Wb1 = (const float*)d_in[12];
    const float* bb1 = (const float*)d_in[13];

    int nnz   = in_sizes[0];
    int batch = in_sizes[4];
    float* out = (float*)d_out;

    size_t emb = (size_t)N_NODES_C * D;
    float* A      = (float*)d_ws;                  // e1c [M x 64]
    float* Sbuf   = A + emb;                       // side_c; aliases pairs1 / layer2 compacts
    int*   bcur   = (int*)(Sbuf + emb);            // NB*CPAD
    int*   scur   = bcur + NB * CPAD;              // NSUP*CPAD
    int*   rp     = scur + NSUP * CPAD;            // NB*65 (+pad)
    int*   idx    = rp + NB * 65 + 2;              // [N]
    int*   list   = idx + N_NODES_C;               // [N]
    int*   bsum   = list + N_NODES_C;              // [1024]
    int*   Mptr   = bsum + 1024;                   // [4]
    unsigned char* need = (unsigned char*)(Mptr + 4);        // [N]
    unsigned char* samp = need + N_NODES_C;                  // [N]
    int2*  pairs  = (int2*)(((size_t)(samp + N_NODES_C) + 15) & ~(size_t)15);  // NB*FCAP

    int2*  pairs1 = (int2*)Sbuf;                   // build-time only (NSUP*SCAP*8 = 21.8MB)
    float* side2c = Sbuf;                          // layer-2 compacts (after transform1)
    float* egoc   = Sbuf + (size_t)2 * 2048 * D;
    float* e2c    = egoc + (size_t)2 * 2048 * D;

    int nscan = (N_NODES_C + 1023) / 1024;         // 147

    // --- needed-set mark + compact ---
    hipMemsetAsync(need, 0, 2 * N_NODES_C, stream);
    mark1_k<<<(2 * batch + 255) / 256, 256, 0, stream>>>(users, items, samp, need, batch);
    mark2_k<<<1024, 256, 0, stream>>>(rows, cols, samp, need, nnz);
    scan1_k<<<nscan, 1024, 0, stream>>>(need, idx, bsum, N_NODES_C);
    scan2_k<<<1, 1024, 0, stream>>>(bsum, nscan, Mptr);
    scan3_k<<<(N_NODES_C + 255) / 256, 256, 0, stream>>>(bsum, idx, need, list, N_NODES_C);

    // --- fixed-capacity two-level bucket build (no histogram, no scan) ---
    initcur_k<<<(NB + 255) / 256, 256, 0, stream>>>(bcur, scur);
    int g1 = (nnz + 2343) / 2344;                  // chunk <= S1CAP
    s1_k<<<g1, 256, 0, stream>>>(rows, cols, vals, idx, scur, pairs1, nnz);
    s2_k<<<NSUP * BPS, 256, 0, stream>>>(scur, pairs1, bcur, pairs);
    sortb_k<<<NB, 256, 0, stream>>>(bcur, pairs, rp);

    // --- Layer 1 over M needed rows (worst-case grid, early exit on M) ---
    gather1_k<<<(N_NODES_C * 64 + 255) / 256, 256, 0, stream>>>(
        rp, pairs, x, Sbuf, Mptr);
    transform_k<<<(N_NODES_C + 63) / 64, 256, 0, stream>>>(
        Sbuf, x, Wg0, bg0, Wb0, bb0, A, list, Mptr, 0);

    // --- Layer 2 (sampled 2*batch rows) ---
    gather2_k<<<(2 * batch * 64 + 255) / 256, 256, 0, stream>>>(
        rp, pairs, A, idx, side2c, egoc, users, items, batch);
    transform_k<<<(2 * batch + 63) / 64, 256, 0, stream>>>(
        side2c, egoc, Wg1, bg1, Wb1, bb1, e2c, nullptr, nullptr, 2 * batch);

    // --- Readout ---
    gamma_k<<<(batch * 64 + 255) / 256, 256, 0, stream>>>(
        x, A, idx, e2c, users, items, out, batch);
}

// Round 10
// 275.908 us; speedup vs baseline: 1.3104x; 1.0747x over previous
//
#include <hip/hip_runtime.h>

#define N_USERS_C 100000
#define N_NODES_C 150000
#define D 64
#define NB 2344              // ceil(150000/64) fine buckets (compact-row space)
#define NSUP 74              // ceil(150000/2048) super buckets
#define CPAD 16              // global cursor padding: 1 int per 64B line
#define SPAD 68              // transform transposed-tile row stride
#define FCAP 1536            // fixed fine-bucket capacity (mean ~1030)
#define S1B 256              // s1 blocks
#define FRAG 240             // per-(block,super) fragment capacity (mean 128, +10 sigma)
#define S2CAP 2560           // s2 per-block staging capacity (mean 2048, +11 sigma)
#define BPS 16               // blocks per super in s2
#define FPB (S1B / BPS)      // fragments per s2 block = 16

// ---------------- Needed-set marking ----------------
__global__ __launch_bounds__(256) void mark1_k(
    const int* __restrict__ u, const int* __restrict__ it,
    unsigned char* __restrict__ samp, unsigned char* __restrict__ need, int batch)
{
    int i = blockIdx.x * blockDim.x + threadIdx.x;
    if (i >= 2 * batch) return;
    int n = (i < batch) ? u[i] : N_USERS_C + it[i - batch];
    samp[n] = 1;
    need[n] = 1;
}

__global__ __launch_bounds__(256) void mark2_k(
    const int* __restrict__ rows, const int* __restrict__ cols,
    const unsigned char* __restrict__ samp, unsigned char* __restrict__ need, int nnz)
{
    int gtid = blockIdx.x * blockDim.x + threadIdx.x;
    int stride = gridDim.x * blockDim.x;
    for (int e = gtid; e < nnz; e += stride)
        if (samp[rows[e]]) need[cols[e]] = 1;
}

// ---------------- 3-kernel scan over need flags -> idx / list / M ----------------
__global__ __launch_bounds__(1024) void scan1_k(
    const unsigned char* __restrict__ need, int* __restrict__ part,
    int* __restrict__ bsum, int n)
{
    __shared__ int wsum[16];
    int i = blockIdx.x * 1024 + threadIdx.x;
    int lane = threadIdx.x & 63, wid = threadIdx.x >> 6;
    int v = (i < n) ? (int)need[i] : 0;
    int incl = v;
    #pragma unroll
    for (int off = 1; off < 64; off <<= 1) {
        int t = __shfl_up(incl, off);
        if (lane >= off) incl += t;
    }
    if (lane == 63) wsum[wid] = incl;
    __syncthreads();
    int woff = 0;
    for (int w = 0; w < wid; ++w) woff += wsum[w];
    if (i < n) part[i] = woff + incl - v;
    if (threadIdx.x == 1023) bsum[blockIdx.x] = woff + incl;
}

__global__ __launch_bounds__(1024) void scan2_k(
    int* __restrict__ bsum, int nb, int* __restrict__ Mptr)
{
    __shared__ int wsum[16];
    int lane = threadIdx.x & 63, wid = threadIdx.x >> 6;
    int i = threadIdx.x;
    int v = (i < nb) ? bsum[i] : 0;
    int incl = v;
    #pragma unroll
    for (int off = 1; off < 64; off <<= 1) {
        int t = __shfl_up(incl, off);
        if (lane >= off) incl += t;
    }
    if (lane == 63) wsum[wid] = incl;
    __syncthreads();
    int woff = 0;
    for (int w = 0; w < wid; ++w) woff += wsum[w];
    if (i < nb) bsum[i] = woff + incl - v;
    if (i == nb - 1) Mptr[0] = woff + incl;
}

// idx[n] = compact index if needed else -1 ; list[compact] = n
__global__ __launch_bounds__(256) void scan3_k(
    const int* __restrict__ bsum, int* __restrict__ idx,
    const unsigned char* __restrict__ need, int* __restrict__ list, int n)
{
    int i = blockIdx.x * blockDim.x + threadIdx.x;
    if (i >= n) return;
    int t = idx[i] + bsum[i >> 10];
    if (need[i]) { idx[i] = t; list[t] = i; }
    else idx[i] = -1;
}

// ---------------- Cursor init: fixed-capacity fine-bucket bases ----------------
__global__ __launch_bounds__(256) void initcur_k(int* __restrict__ bcur)
{
    int i = blockIdx.x * blockDim.x + threadIdx.x;
    if (i < NB) bcur[i * CPAD] = i * FCAP;
}

// ---------------- S1: single-pass scatter into private per-(block,super) fragments ----------------
// NO global atomics, NO second edge pass. pairs1[sp*(S1B*FRAG) + b*FRAG + k].
// pairs1[p].x = ((crow & 2047) << 18) | col ; scnt[sp*S1B + b] = fragment length.
__global__ __launch_bounds__(512) void s1_k(
    const int* __restrict__ rows, const int* __restrict__ cols,
    const float* __restrict__ vals, const int* __restrict__ idx,
    int2* __restrict__ pairs1, int* __restrict__ scnt, int nnz)
{
    __shared__ int lcur[NSUP];
    int t = threadIdx.x;
    for (int i = t; i < NSUP; i += 512) lcur[i] = 0;
    __syncthreads();
    int b = blockIdx.x;
    int per = (nnz + S1B - 1) / S1B;
    int s = b * per;
    int e = min(nnz, s + per);
    for (int i = s + t; i < e; i += 512) {
        int ci = idx[rows[i]];
        if (ci < 0) continue;
        int sp = ci >> 11;
        int k = atomicAdd(&lcur[sp], 1);
        pairs1[(size_t)sp * (S1B * FRAG) + b * FRAG + k] =
            make_int2(((ci & 2047) << 18) | cols[i], __float_as_int(vals[i]));
    }
    __syncthreads();
    for (int i = t; i < NSUP; i += 512) scnt[i * S1B + b] = lcur[i];
}

// ---------------- S2: gather fragments of one super-part, scatter to fine buckets ----------------
__global__ __launch_bounds__(256) void s2_k(
    const int* __restrict__ scnt, const int2* __restrict__ pairs1,
    int* __restrict__ bcurP, int2* __restrict__ pairs)
{
    __shared__ int2 sbuf[S2CAP];
    __shared__ int fcnt[32], fcur[32], gb[32];
    int sp = blockIdx.x / BPS, part = blockIdx.x % BPS;
    int t = threadIdx.x;
    if (t < 32) { fcnt[t] = 0; fcur[t] = 0; }
    __syncthreads();
    int base = 0;
    for (int fi = 0; fi < FPB; ++fi) {
        int b = part * FPB + fi;
        int m = scnt[sp * S1B + b];
        const int2* src = &pairs1[(size_t)sp * (S1B * FRAG) + b * FRAG];
        for (int i = t; i < m; i += 256) {
            int2 p = src[i];
            sbuf[base + i] = p;
            atomicAdd(&fcnt[(p.x >> 18) >> 6], 1);
        }
        base += m;
    }
    __syncthreads();
    if (t < 32) {
        int c = fcnt[t];
        gb[t] = c ? atomicAdd(&bcurP[(sp * 32 + t) * CPAD], c) : 0;
    }
    __syncthreads();
    for (int i = t; i < base; i += 256) {
        int2 p = sbuf[i];
        int ris = p.x >> 18;
        int f = ris >> 6;
        int k = atomicAdd(&fcur[f], 1);
        pairs[gb[f] + k] = make_int2(((ris & 63) << 18) | (p.x & 0x3FFFF), p.y);
    }
}

// ---------------- Per-bucket LDS counting sort -> per-row ranges ----------------
// rp[b*65 + j] = start of row j in bucket b; rp[b*65 + 64] = bucket end.
__global__ __launch_bounds__(256) void sortb_k(
    const int* __restrict__ bcurP, int2* __restrict__ pairs,
    int* __restrict__ rp)
{
    __shared__ int2 buf[FCAP];
    __shared__ int cnt[64];
    __shared__ int cur[64];
    int b = blockIdx.x;
    int s = b * FCAP;
    int e = bcurP[b * CPAD];
    int m = e - s;
    int t = threadIdx.x;
    if (t < 64) cnt[t] = 0;
    __syncthreads();
    for (int i = t; i < m; i += 256) {
        int2 p = pairs[s + i];
        buf[i] = p;
        atomicAdd(&cnt[p.x >> 18], 1);
    }
    __syncthreads();
    if (t < 64) {
        int v = cnt[t];
        int incl = v;
        #pragma unroll
        for (int o = 1; o < 64; o <<= 1) {
            int u = __shfl_up(incl, o);
            if (t >= o) incl += u;
        }
        cur[t] = incl - v;
        rp[b * 65 + t] = s + incl - v;
        if (t == 63) rp[b * 65 + 64] = s + incl;
    }
    __syncthreads();
    for (int i = t; i < m; i += 256) {
        int2 p = buf[i];
        int dst = atomicAdd(&cur[p.x >> 18], 1);
        pairs[s + dst] = make_int2(p.x & 0x3FFFF, p.y);
    }
}

// ---------------- Layer-1 gather: one wave per needed (compact) row ----------------
__global__ __launch_bounds__(256) void gather1_k(
    const int* __restrict__ rp, const int2* __restrict__ pairs,
    const float* __restrict__ x, float* __restrict__ side,
    const int* __restrict__ Mptr)
{
    int gtid = blockIdx.x * blockDim.x + threadIdx.x;
    int wave = gtid >> 6;
    int lane = threadIdx.x & 63;
    if (wave >= Mptr[0]) return;
    int rb = (wave >> 6) * 65 + (wave & 63);
    int s  = rp[rb];
    int ep = rp[rb + 1];

    float acc = 0.0f;
    for (int base = s; base < ep; base += 64) {
        int2 p = make_int2(0, 0);
        if (base + lane < ep) p = pairs[base + lane];
        int cnt4 = (min(ep - base, 64) + 3) & ~3;
        for (int j = 0; j < cnt4; j += 4) {
            int c0 = __shfl(p.x, j + 0);
            int c1 = __shfl(p.x, j + 1);
            int c2 = __shfl(p.x, j + 2);
            int c3 = __shfl(p.x, j + 3);
            float v0 = __int_as_float(__shfl(p.y, j + 0));
            float v1 = __int_as_float(__shfl(p.y, j + 1));
            float v2 = __int_as_float(__shfl(p.y, j + 2));
            float v3 = __int_as_float(__shfl(p.y, j + 3));
            float f0 = x[(size_t)c0 * D + lane];
            float f1 = x[(size_t)c1 * D + lane];
            float f2 = x[(size_t)c2 * D + lane];
            float f3 = x[(size_t)c3 * D + lane];
            acc = fmaf(v0, f0, acc);
            acc = fmaf(v1, f1, acc);
            acc = fmaf(v2, f2, acc);
            acc = fmaf(v3, f3, acc);
        }
    }
    side[(size_t)wave * D + lane] = acc;
}

// ---------------- Layer-2 gather (sampled): e1 via compact idx ----------------
__global__ __launch_bounds__(256) void gather2_k(
    const int* __restrict__ rp, const int2* __restrict__ pairs,
    const float* __restrict__ e1c, const int* __restrict__ idx,
    float* __restrict__ side2c, float* __restrict__ egoc,
    const int* __restrict__ u, const int* __restrict__ it, int batch)
{
    int gtid = blockIdx.x * blockDim.x + threadIdx.x;
    int wave = gtid >> 6;
    int lane = threadIdx.x & 63;
    if (wave >= 2 * batch) return;
    int n = (wave < batch) ? u[wave] : N_USERS_C + it[wave - batch];
    int cr = idx[n];
    int rb = (cr >> 6) * 65 + (cr & 63);
    int s  = rp[rb];
    int ep = rp[rb + 1];

    float acc = 0.0f;
    for (int base = s; base < ep; base += 64) {
        int2 p = make_int2(0, 0);
        if (base + lane < ep) p = pairs[base + lane];
        int cnt = min(ep - base, 64);
        for (int j = 0; j < cnt; ++j) {
            int   c = __shfl(p.x, j);
            float v = __int_as_float(__shfl(p.y, j));
            acc = fmaf(v, e1c[(size_t)idx[c] * D + lane], acc);
        }
    }
    side2c[(size_t)wave * D + lane] = acc;
    egoc[(size_t)wave * D + lane] = e1c[(size_t)cr * D + lane];
}

// ---------------- Tiled transform ----------------
__global__ __launch_bounds__(256) void transform_k(
    const float* __restrict__ S, const float* __restrict__ Eb,
    const float* __restrict__ Wg, const float* __restrict__ bg,
    const float* __restrict__ Wb, const float* __restrict__ bb,
    float* __restrict__ out, const int* __restrict__ list,
    const int* __restrict__ Mptr, int nrows)
{
    __shared__ __align__(16) float sWg[D * D];
    __shared__ __align__(16) float sWb[D * D];
    __shared__ __align__(16) float sAT[D][SPAD];
    __shared__ __align__(16) float sBT[D][SPAD];

    int nr = Mptr ? Mptr[0] : nrows;
    int t  = threadIdx.x;
    int tc = t & 15;
    int tr = t >> 4;
    int r0 = blockIdx.x * 64;
    if (r0 >= nr) return;

    for (int i = t; i < D * D; i += 256) {
        sWg[i] = Wg[i];
        sWb[i] = Wb[i];
    }
    for (int itr = 0; itr < 4; ++itr) {
        int rr  = itr * 16 + (t >> 4);
        int row = r0 + rr;
        float4 sv = make_float4(0.f, 0.f, 0.f, 0.f);
        float4 ev = sv;
        if (row < nr) {
            sv = *(const float4*)&S[(size_t)row * D + tc * 4];
            int er = list ? list[row] : row;
            ev = *(const float4*)&Eb[(size_t)er * D + tc * 4];
        }
        sAT[tc * 4 + 0][rr] = sv.x;
        sAT[tc * 4 + 1][rr] = sv.y;
        sAT[tc * 4 + 2][rr] = sv.z;
        sAT[tc * 4 + 3][rr] = sv.w;
        sBT[tc * 4 + 0][rr] = sv.x * ev.x;
        sBT[tc * 4 + 1][rr] = sv.y * ev.y;
        sBT[tc * 4 + 2][rr] = sv.z * ev.z;
        sBT[tc * 4 + 3][rr] = sv.w * ev.w;
    }
    __syncthreads();

    float acc[4][4] = {};
    for (int k = 0; k < D; ++k) {
        float4 a4 = *(const float4*)&sAT[k][tr * 4];
        float4 b4 = *(const float4*)&sBT[k][tr * 4];
        float4 g4 = *(const float4*)&sWg[k * D + tc * 4];
        float4 w4 = *(const float4*)&sWb[k * D + tc * 4];
        float av[4] = {a4.x, a4.y, a4.z, a4.w};
        float bv[4] = {b4.x, b4.y, b4.z, b4.w};
        float gv[4] = {g4.x, g4.y, g4.z, g4.w};
        float wv[4] = {w4.x, w4.y, w4.z, w4.w};
        #pragma unroll
        for (int i = 0; i < 4; ++i)
            #pragma unroll
            for (int j = 0; j < 4; ++j)
                acc[i][j] = fmaf(av[i], gv[j], fmaf(bv[i], wv[j], acc[i][j]));
    }

    float4 bgv = *(const float4*)&bg[tc * 4];
    float4 bbv = *(const float4*)&bb[tc * 4];
    float bias[4] = {bgv.x + bbv.x, bgv.y + bbv.y, bgv.z + bbv.z, bgv.w + bbv.w};

    float vv[4][4];
    float ss[4] = {0.f, 0.f, 0.f, 0.f};
    #pragma unroll
    for (int i = 0; i < 4; ++i) {
        #pragma unroll
        for (int j = 0; j < 4; ++j) {
            float v = acc[i][j] + bias[j];
            v = (v > 0.0f) ? v : 0.2f * v;
            vv[i][j] = v;
            ss[i] += v * v;
        }
    }
    #pragma unroll
    for (int i = 0; i < 4; ++i) {
        #pragma unroll
        for (int off = 1; off < 16; off <<= 1)
            ss[i] += __shfl_xor(ss[i], off);
    }
    #pragma unroll
    for (int i = 0; i < 4; ++i) {
        int row = r0 + tr * 4 + i;
        if (row < nr) {
            float inv = 1.0f / fmaxf(sqrtf(ss[i]), 1e-12f);
            float4 o = make_float4(vv[i][0] * inv, vv[i][1] * inv,
                                   vv[i][2] * inv, vv[i][3] * inv);
            *(float4*)&out[(size_t)row * D + tc * 4] = o;
        }
    }
}

// ---------------- Readout ----------------
__global__ __launch_bounds__(256) void gamma_k(
    const float* __restrict__ x, const float* __restrict__ e1c,
    const int* __restrict__ idx, const float* __restrict__ e2c,
    const int* __restrict__ users, const int* __restrict__ items,
    float* __restrict__ gamma, int batch)
{
    int gtid = blockIdx.x * blockDim.x + threadIdx.x;
    int wave = gtid >> 6;
    int lane = threadIdx.x & 63;
    if (wave >= batch) return;
    size_t uu = (size_t)users[wave];
    size_t tt = (size_t)(N_USERS_C + items[wave]);
    float acc = x[uu * D + lane] * x[tt * D + lane]
              + e1c[(size_t)idx[uu] * D + lane] * e1c[(size_t)idx[tt] * D + lane]
              + e2c[(size_t)wave * D + lane] * e2c[(size_t)(batch + wave) * D + lane];
    #pragma unroll
    for (int off = 1; off < 64; off <<= 1) acc += __shfl_xor(acc, off);
    if (lane == 0) gamma[wave] = acc;
}

extern "C" void kernel_launch(void* const* d_in, const int* in_sizes, int n_in,
                              void* d_out, int out_size, void* d_ws, size_t ws_size,
                              hipStream_t stream) {
    const int*   rows  = (const int*)d_in[0];
    const int*   cols  = (const int*)d_in[1];
    const float* vals  = (const float*)d_in[2];
    const float* x     = (const float*)d_in[3];
    const int*   users = (const int*)d_in[4];
    const int*   items = (const int*)d_in[5];
    const float* Wg0 = (const float*)d_in[6];
    const float* bg0 = (const float*)d_in[7];
    const float* Wb0 = (const float*)d_in[8];
    const float* bb0 = (const float*)d_in[9];
    const float* Wg1 = (const float*)d_in[10];
    const float* bg1 = (const float*)d_in[11];
    const float* Wb1 = (const float*)d_in[12];
    const float* bb1 = (const float*)d_in[13];

    int nnz   = in_sizes[0];
    int batch = in_sizes[4];
    float* out = (float*)d_out;

    size_t emb = (size_t)N_NODES_C * D;
    float* A      = (float*)d_ws;                  // e1c [M x 64]
    float* Sbuf   = A + emb;                       // side_c; aliases pairs1 / layer2 compacts
    int*   bcur   = (int*)(Sbuf + emb);            // NB*CPAD
    int*   rp     = bcur + NB * CPAD;              // NB*65 (+pad)
    int*   idx    = rp + NB * 65 + 2;              // [N]
    int*   list   = idx + N_NODES_C;               // [N]
    int*   bsum   = list + N_NODES_C;              // [1024]
    int*   Mptr   = bsum + 1024;                   // [4]
    int*   scnt   = Mptr + 4;                      // [NSUP*S1B]
    unsigned char* need = (unsigned char*)(scnt + NSUP * S1B);   // [N]
    unsigned char* samp = need + N_NODES_C;                      // [N]
    int2*  pairs  = (int2*)(((size_t)(samp + N_NODES_C) + 15) & ~(size_t)15);  // NB*FCAP

    int2*  pairs1 = (int2*)Sbuf;                   // build-time only (74*256*240*8 = 36.4MB < 38.4MB)
    float* side2c = Sbuf;                          // layer-2 compacts (after s2 consumed pairs1)
    float* egoc   = Sbuf + (size_t)2 * 2048 * D;
    float* e2c    = egoc + (size_t)2 * 2048 * D;

    int nscan = (N_NODES_C + 1023) / 1024;         // 147

    // --- needed-set mark + compact ---
    hipMemsetAsync(need, 0, 2 * N_NODES_C, stream);
    mark1_k<<<(2 * batch + 255) / 256, 256, 0, stream>>>(users, items, samp, need, batch);
    mark2_k<<<1024, 256, 0, stream>>>(rows, cols, samp, need, nnz);
    scan1_k<<<nscan, 1024, 0, stream>>>(need, idx, bsum, N_NODES_C);
    scan2_k<<<1, 1024, 0, stream>>>(bsum, nscan, Mptr);
    scan3_k<<<(N_NODES_C + 255) / 256, 256, 0, stream>>>(bsum, idx, need, list, N_NODES_C);

    // --- bucket build: private fragments (no global atomics in s1) ---
    initcur_k<<<(NB + 255) / 256, 256, 0, stream>>>(bcur);
    s1_k<<<S1B, 512, 0, stream>>>(rows, cols, vals, idx, pairs1, scnt, nnz);
    s2_k<<<NSUP * BPS, 256, 0, stream>>>(scnt, pairs1, bcur, pairs);
    sortb_k<<<NB, 256, 0, stream>>>(bcur, pairs, rp);

    // --- Layer 1 over M needed rows (worst-case grid, early exit on M) ---
    gather1_k<<<(N_NODES_C * 64 + 255) / 256, 256, 0, stream>>>(
        rp, pairs, x, Sbuf, Mptr);
    transform_k<<<(N_NODES_C + 63) / 64, 256, 0, stream>>>(
        Sbuf, x, Wg0, bg0, Wb0, bb0, A, list, Mptr, 0);

    // --- Layer 2 (sampled 2*batch rows) ---
    gather2_k<<<(2 * batch * 64 + 255) / 256, 256, 0, stream>>>(
        rp, pairs, A, idx, side2c, egoc, users, items, batch);
    transform_k<<<(2 * batch + 63) / 64, 256, 0, stream>>>(
        side2c, egoc, Wg1, bg1, Wb1, bb1, e2c, nullptr, nullptr, 2 * batch);

    // --- Readout ---
    gamma_k<<<(batch * 64 + 255) / 256, 256, 0, stream>>>(
        x, A, idx, e2c, users, items, out, batch);
}